// Round 12
// baseline (263.274 us; speedup 1.0000x reference)
//
#include <hip/hip_runtime.h>
#include <hip/hip_bf16.h>

// Problem constants
#define B_   4
#define T_   2048
#define C_   1024
#define H_   16
#define HD_  64
#define BH_  (B_*H_)    // 64
#define M_   (B_*T_)    // 8192
#define N1_  (3*C_)     // 3072

typedef __hip_bfloat16 bf16;
typedef __attribute__((ext_vector_type(8))) __bf16 bf16x8v;   // MFMA A/B frag (4 VGPRs)
typedef __attribute__((ext_vector_type(4))) float  f32x4;     // MFMA C/D frag

// Q pre-scale: 1/sqrt(64) * log2(e)  -> softmax computed with exp2 (1 v_exp_f32)
#define QSCALE 0.18033688f

__device__ __forceinline__ f32x4 mfma16(bf16x8v a, bf16x8v b, f32x4 c) {
    return __builtin_amdgcn_mfma_f32_16x16x32_bf16(a, b, c, 0, 0, 0);
}

__device__ __forceinline__ float exp2_hw(float x) {
    return __builtin_amdgcn_exp2f(x);
}

// async global->LDS DMA, 16 B per lane (lds dest = wave-uniform base + lane*16).
// Side-effecting: compiler cannot sink it across the barrier (r9 lesson).
typedef __attribute__((address_space(3))) unsigned int       lds_u32;
typedef const __attribute__((address_space(1))) unsigned int glb_u32;
__device__ __forceinline__ void async16(void* lds, const void* g) {
    __builtin_amdgcn_global_load_lds((glb_u32*)g, (lds_u32*)lds, 16, 0, 0);
}

// ---------------------------------------------------------------------------
// prep: fused pre-pass (saves 2 launch gaps).
//   blocks [0,4096):        x fp32 -> bf16 (8 elems/thread)
//   blocks [4096,7168):     w_qkv transpose+convert -> wtqkv [3072][1024]
//   blocks [7168,8192):     w_out transpose+convert -> wtout [1024][1024]
// ---------------------------------------------------------------------------
__global__ void prep(const float* __restrict__ x,  bf16* __restrict__ xb,
                     const float* __restrict__ wq, bf16* __restrict__ wqt,
                     const float* __restrict__ wo, bf16* __restrict__ wot)
{
    __shared__ float t[32][33];
    const int bid = blockIdx.x;
    if (bid < 4096) {
        const int i = bid * 256 + threadIdx.x;
        float f[8];
        *(float4*)(f)     = ((const float4*)x)[(size_t)i*2];
        *(float4*)(f + 4) = ((const float4*)x)[(size_t)i*2 + 1];
        bf16 tb[8];
#pragma unroll
        for (int j = 0; j < 8; ++j) tb[j] = __float2bfloat16(f[j]);
        ((uint4*)xb)[i] = *(uint4*)tb;
        return;
    }
    const float* in; bf16* out; int K, N, n0, k0;
    if (bid < 7168) { const int b2 = bid - 4096; in = wq; out = wqt; K = C_; N = N1_;
                      n0 = (b2 % 96) * 32; k0 = (b2 / 96) * 32; }
    else            { const int b2 = bid - 7168; in = wo; out = wot; K = C_; N = C_;
                      n0 = (b2 % 32) * 32; k0 = (b2 / 32) * 32; }
    const int c  = threadIdx.x & 31;
    const int rr = threadIdx.x >> 5;
#pragma unroll
    for (int i = 0; i < 4; ++i)
        t[c][rr + 8*i] = in[(size_t)(k0 + rr + 8*i) * N + n0 + c];
    __syncthreads();
#pragma unroll
    for (int i = 0; i < 4; ++i)
        out[(size_t)(n0 + rr + 8*i) * K + k0 + c] = __float2bfloat16(t[rr + 8*i][c]);
}

// ---------------------------------------------------------------------------
// GEMM (r8-exact, best measured 82 us / 633 TF): C = A(bf16)[M,K] @ Bt(bf16)[N,K].
// 128x128 tile, BK=64, single 32 KB LDS, global_load_lds width=16.
// XOR swizzle (verified SQ_LDS_BANK_CONFLICT = 0). r9 (reg-pipeline: compiler
// sank loads, 4.3x regr) and r10 (LDS dbuf: occupancy loss, 1.18x regr)
// confirmed this is the plateau shape for this structure.
// ---------------------------------------------------------------------------
template<int EPI>
__global__ __launch_bounds__(256, 2)
void gemm_lds(const bf16* __restrict__ A, const bf16* __restrict__ Bt,
              float* __restrict__ Cmat, int N, int K,
              bf16* __restrict__ qb, bf16* __restrict__ kb, bf16* __restrict__ vb)
{
    __shared__ bf16 Alds[128][64];   // 16 KB
    __shared__ bf16 Blds[128][64];   // 16 KB

    const int tid  = threadIdx.x;
    const int wave = tid >> 6, lane = tid & 63;
    const int quad = lane >> 4, l16 = lane & 15;
    const int wm   = (wave >> 1) * 64, wn = (wave & 1) * 64;
    const size_t row0 = (size_t)blockIdx.y * 128;
    const size_t col0 = (size_t)blockIdx.x * 128;

    const f32x4 z4 = {0.f, 0.f, 0.f, 0.f};
    f32x4 acc[4][4];
#pragma unroll
    for (int mi = 0; mi < 4; ++mi)
#pragma unroll
        for (int ni = 0; ni < 4; ++ni) acc[mi][ni] = z4;

    const int grow = lane >> 3;                       // 0..7
    const int gcol = ((lane & 7) ^ (lane >> 3)) * 8;  // swizzled granule
    const bf16* pA = A  + (row0 + wave*32 + grow) * (size_t)K + gcol;
    const bf16* pB = Bt + (col0 + wave*32 + grow) * (size_t)K + gcol;
    bf16* lA = &Alds[wave*32][0];
    bf16* lB = &Blds[wave*32][0];

    const int fsw = l16 & 7;

    for (int k0 = 0; k0 < K; k0 += 64) {
#pragma unroll
        for (int j = 0; j < 4; ++j)
            async16(lA + j*512, pA + (size_t)j*8*K + k0);
#pragma unroll
        for (int j = 0; j < 4; ++j)
            async16(lB + j*512, pB + (size_t)j*8*K + k0);
        __syncthreads();

#pragma unroll
        for (int kp = 0; kp < 2; ++kp) {
            const int fg = ((kp*4 + quad) ^ fsw) * 8;
            bf16x8v af[4], bfr[4];
#pragma unroll
            for (int i = 0; i < 4; ++i) {
                af[i]  = *(const bf16x8v*)(&Alds[wm + i*16 + l16][fg]);
                bfr[i] = *(const bf16x8v*)(&Blds[wn + i*16 + l16][fg]);
            }
#pragma unroll
            for (int mi = 0; mi < 4; ++mi)
#pragma unroll
                for (int ni = 0; ni < 4; ++ni)
                    acc[mi][ni] = mfma16(af[mi], bfr[ni], acc[mi][ni]);
        }
        __syncthreads();
    }

#pragma unroll
    for (int mi = 0; mi < 4; ++mi) {
        const size_t rowb = row0 + wm + mi*16 + quad*4;
#pragma unroll
        for (int ni = 0; ni < 4; ++ni) {
            const size_t col = col0 + wn + ni*16 + l16;
#pragma unroll
            for (int r = 0; r < 4; ++r) {
                const float v = acc[mi][ni][r];
                if constexpr (EPI == 0) {
                    Cmat[(rowb + r) * N + col] = v;
                } else {
                    const int rowi = (int)(rowb + r);
                    const int b  = rowi >> 11;
                    const int t  = rowi & (T_ - 1);
                    const int coli = (int)col;
                    const int type = coli >> 10;
                    const int cc2  = coli & (C_ - 1);
                    const int h = cc2 >> 6, d = cc2 & (HD_ - 1);
                    const int bh = b * H_ + h;
                    if (type == 0)
                        qb[((size_t)bh * T_ + t) * HD_ + d] = __float2bfloat16(v * QSCALE);
                    else if (type == 1)
                        kb[((size_t)bh * T_ + t) * HD_ + d] = __float2bfloat16(v);
                    else
                        vb[((size_t)bh * HD_ + d) * T_ + t] = __float2bfloat16(v);
                }
            }
        }
    }
}

// ---------------------------------------------------------------------------
// Flash attention v8 (causal): KEY-SPLIT WAVE GROUPS.
// 512 threads = 2 groups x 4 waves. Group g processes key chunks
// k0 = g*64 + 128j — static-max softmax makes l and O pure sums over keys,
// so groups merge by ADDITION in the epilogue (no max coordination).
// Each group: r8's verified per-wave math (nq=2 rows=32/wave, permuted-key
// S^T with C-frag in-lane == PV A-frag, in-lane exp2 pack) + private dbuf
// K/V LDS, sharing one block-wide barrier per iteration.
// vs r8: 16 waves/CU (2x), barrier periods 34 -> 17, same LDS intensity.
// Pairs {bx,15-bx}: per tile both groups run exactly ti+1 iterations.
// ---------------------------------------------------------------------------
#define KP2 72

__global__ __launch_bounds__(512, 4)
void attn_ks(const bf16* __restrict__ qb, const bf16* __restrict__ kb,
             const bf16* __restrict__ vb, bf16* __restrict__ attn)
{
    __shared__ bf16 KV[2][2][2][64][KP2];   // [K/V][group][parity][row][col] 72 KB
    __shared__ float Ls0[4][2][16];         // group-0 per-row l
    __shared__ float Lt[4][2][16];          // total l redistribute
    float* Os = (float*)&KV[0][0][0][0][0]; // [128][68] fp32 epilogue scratch (K region, dead then)

    const int tid  = threadIdx.x;
    const int wave = tid >> 6, lane = tid & 63;
    const int g    = wave >> 2, w2 = wave & 3;
    const int quad = lane >> 4, l16 = lane & 15;
    const int bh   = blockIdx.y;

    const bf16* Q  = qb + (size_t)bh * T_ * HD_;
    const bf16* Kp = kb + (size_t)bh * T_ * HD_;
    const bf16* Vp = vb + (size_t)bh * HD_ * T_;

    const int ltid = tid & 255;       // thread index within group
    const int kr = ltid >> 3;         // 0..31
    const int kc = (ltid & 7) * 8;    // 0..56

    const int b = bh >> 4, h = bh & (H_ - 1);
    const f32x4 z4 = {0.f, 0.f, 0.f, 0.f};
    const int krow_base = ((l16 >> 2) * 8) + (l16 & 3);
    const int tiles[2] = { (int)blockIdx.x, 15 - (int)blockIdx.x };

    // preload this group's first chunk (keys g*64 .. g*64+63)
    uint4 kreg0 = *(const uint4*)(Kp + (size_t)(g*64 + kr)      * HD_ + kc);
    uint4 kreg1 = *(const uint4*)(Kp + (size_t)(g*64 + kr + 32) * HD_ + kc);
    uint4 vreg0 = *(const uint4*)(Vp + (size_t)kr        * T_ + g*64 + kc);
    uint4 vreg1 = *(const uint4*)(Vp + (size_t)(kr + 32) * T_ + g*64 + kc);

    int p = 0;   // parity, runs continuously across both tiles (same for both groups)

#pragma unroll 1
    for (int tt = 0; tt < 2; ++tt) {
        const int ti  = tiles[tt];
        const int q0b = ti * 128;
        const int q0w = q0b + w2 * 32;

        // Q frags [nq][kp]: B-operand layout n=l16 (qrow), k=quad*8+j (d)
        bf16x8v qf[2][2];
#pragma unroll
        for (int nq = 0; nq < 2; ++nq)
#pragma unroll
            for (int kp = 0; kp < 2; ++kp)
                qf[nq][kp] = *(const bf16x8v*)(Q + (size_t)(q0w + nq*16 + l16) * HD_ + kp*32 + quad*8);

        f32x4 o[2][4];
#pragma unroll
        for (int nq = 0; nq < 2; ++nq)
#pragma unroll
            for (int di = 0; di < 4; ++di) o[nq][di] = z4;
        float l_nq[2] = {0.f, 0.f};

        const int iters = ti + 1;   // per-group iterations this tile (equal for g=0,1)

#pragma unroll 1
        for (int j = 0; j < iters; ++j) {
            const int k0 = g*64 + j*128;
            // stage prefetched regs into this group's buffer [p]
            *(uint4*)(&KV[0][g][p][kr][kc])      = kreg0;
            *(uint4*)(&KV[0][g][p][kr + 32][kc]) = kreg1;
            *(uint4*)(&KV[1][g][p][kr][kc])      = vreg0;
            *(uint4*)(&KV[1][g][p][kr + 32][kc]) = vreg1;
            __syncthreads();   // single block-wide barrier per iteration

            // prefetch next chunk (or next tile's first chunk for this group)
            const int kn = (j + 1 < iters) ? (k0 + 128) : (g*64);
            kreg0 = *(const uint4*)(Kp + (size_t)(kn + kr)      * HD_ + kc);
            kreg1 = *(const uint4*)(Kp + (size_t)(kn + kr + 32) * HD_ + kc);
            vreg0 = *(const uint4*)(Vp + (size_t)kr        * T_ + kn + kc);
            vreg1 = *(const uint4*)(Vp + (size_t)(kr + 32) * T_ + kn + kc);

            if (k0 <= q0w + 31) {   // wave-uniform causal skip
                // ---- S^T = K·Q^T : 4 permuted key-tiles x 2 qrow-tiles ----
                f32x4 st[4][2];
#pragma unroll
                for (int mk = 0; mk < 4; ++mk)
#pragma unroll
                    for (int nq = 0; nq < 2; ++nq) st[mk][nq] = z4;
#pragma unroll
                for (int kp = 0; kp < 2; ++kp) {
                    bf16x8v kf[4];
#pragma unroll
                    for (int mk = 0; mk < 4; ++mk)
                        kf[mk] = *(const bf16x8v*)(&KV[0][g][p][krow_base + (mk>>1)*32 + (mk&1)*4][kp*32 + quad*8]);
#pragma unroll
                    for (int mk = 0; mk < 4; ++mk) {
                        st[mk][0] = mfma16(kf[mk], qf[0][kp], st[mk][0]);
                        st[mk][1] = mfma16(kf[mk], qf[1][kp], st[mk][1]);
                    }
                }
                // ---- causal mask (chunks straddling the diagonal only) ----
                if (k0 + 63 > q0w) {
#pragma unroll
                    for (int mk = 0; mk < 4; ++mk) {
                        const int keyb = k0 + (mk>>1)*32 + quad*8 + (mk&1)*4;
#pragma unroll
                        for (int nq = 0; nq < 2; ++nq) {
                            const int qrow = q0w + nq*16 + l16;
#pragma unroll
                            for (int r = 0; r < 4; ++r)
                                if (keyb + r > qrow) st[mk][nq][r] = -3.0e38f;
                        }
                    }
                }
                // ---- exp2 + l partials + IN-LANE pack to PV A-frags ----
                bf16x8v pa[2][2];
#pragma unroll
                for (int nq = 0; nq < 2; ++nq) {
#pragma unroll
                    for (int kp = 0; kp < 2; ++kp) {
                        union { bf16x8v v; bf16 hh[8]; } u;
                        float sum = 0.f;
#pragma unroll
                        for (int jh = 0; jh < 2; ++jh) {
                            const int mk = kp*2 + jh;
#pragma unroll
                            for (int r = 0; r < 4; ++r) {
                                const float e = exp2_hw(st[mk][nq][r]);
                                sum += e;
                                u.hh[jh*4 + r] = __float2bfloat16(e);
                            }
                        }
                        l_nq[nq] += sum;
                        pa[nq][kp] = u.v;
                    }
                }
                // ---- O += P V  (V-side key permutation is identity) ----
#pragma unroll
                for (int kp = 0; kp < 2; ++kp)
#pragma unroll
                    for (int di = 0; di < 4; ++di) {
                        const bf16x8v vf = *(const bf16x8v*)(&KV[1][g][p][di*16 + l16][kp*32 + quad*8]);
                        o[0][di] = mfma16(pa[0][kp], vf, o[0][di]);
                        o[1][di] = mfma16(pa[1][kp], vf, o[1][di]);
                    }
            }
            p ^= 1;
        }

        // ---- epilogue: merge groups (pure sums — static-max softmax) ----
        __syncthreads();   // all chunk compute done; K region reusable as Os
        float lr[2];
#pragma unroll
        for (int nq = 0; nq < 2; ++nq) {
            float l = l_nq[nq];
            l += __shfl_xor(l, 16);
            l += __shfl_xor(l, 32);
            lr[nq] = l;
        }
        if (g == 0) {
#pragma unroll
            for (int nq = 0; nq < 2; ++nq) {
                if (quad == 0) Ls0[w2][nq][l16] = lr[nq];
#pragma unroll
                for (int r = 0; r < 4; ++r) {
                    const int row = w2*32 + nq*16 + quad*4 + r;
#pragma unroll
                    for (int di = 0; di < 4; ++di)
                        Os[row*68 + di*16 + l16] = o[nq][di][r];
                }
            }
        }
        __syncthreads();
        if (g == 1) {
#pragma unroll
            for (int nq = 0; nq < 2; ++nq) {
                const float ltot = lr[nq] + Ls0[w2][nq][l16];
                if (quad == 0) Lt[w2][nq][l16] = ltot;
            }
            // wave-internal DS ordering: reads below see this wave's writes
#pragma unroll
            for (int nq = 0; nq < 2; ++nq) {
                const f32x4 lv = *(const f32x4*)(&Lt[w2][nq][quad*4]);
#pragma unroll
                for (int r = 0; r < 4; ++r) {
                    const float inv = 1.0f / lv[r];
                    const int row = w2*32 + nq*16 + quad*4 + r;
                    const int t = q0b + row;
                    const size_t base = ((size_t)(b * T_ + t)) * C_ + h * HD_;
#pragma unroll
                    for (int di = 0; di < 4; ++di)
                        attn[base + di*16 + l16] =
                            __float2bfloat16((o[nq][di][r] + Os[row*68 + di*16 + l16]) * inv);
                }
            }
        }
        __syncthreads();   // protect LDS before next tile's staging
    }
}

// ---------------------------------------------------------------------------
// Workspace layout (MiB from d_ws), total 72 MiB:
//   [ 0,16)  q    bf16 [64][2048][64]  (pre-scaled 0.125*log2e)
//   [16,32)  k    bf16 [64][2048][64]
//   [32,48)  v    bf16 [64][64][2048]  (transposed [bh][d][t])
//   [48,64)  xb   bf16 [8192][1024]  -- aliased -> attnb (xb dead after GEMM1)
//   [64,70)  wt_qkv bf16 [3072][1024]
//   [70,72)  wt_out bf16 [1024][1024]
// ---------------------------------------------------------------------------
extern "C" void kernel_launch(void* const* d_in, const int* in_sizes, int n_in,
                              void* d_out, int out_size, void* d_ws, size_t ws_size,
                              hipStream_t stream)
{
    const float* x     = (const float*)d_in[0];
    const float* w_qkv = (const float*)d_in[1];
    const float* w_out = (const float*)d_in[2];
    float* out = (float*)d_out;

    char* ws = (char*)d_ws;
    bf16* qb     = (bf16*)(ws);
    bf16* kb     = (bf16*)(ws + (size_t)16 * 1024 * 1024);
    bf16* vb     = (bf16*)(ws + (size_t)32 * 1024 * 1024);
    bf16* xb     = (bf16*)(ws + (size_t)48 * 1024 * 1024);
    bf16* attnb  = xb;   // alias: xb consumed by GEMM1 before attn writes
    bf16* wtqkv  = (bf16*)(ws + (size_t)64 * 1024 * 1024);
    bf16* wtout  = (bf16*)(ws + (size_t)70 * 1024 * 1024);

    // 0) fused pre-pass: x->bf16 + both weight transposes (one launch)
    prep<<<dim3(8192), 256, 0, stream>>>(x, xb, w_qkv, wtqkv, w_out, wtout);

    // 1) qkv = xb @ w_qkv, scatter q/k/v  (r8-exact GEMM)
    gemm_lds<1><<<dim3(N1_/128, M_/128), 256, 0, stream>>>(
        xb, wtqkv, nullptr, N1_, C_, qb, kb, vb);

    // 2) causal flash attention, key-split wave groups
    attn_ks<<<dim3(8, BH_), 512, 0, stream>>>(qb, kb, vb, attnb);

    // 3) out = attn @ w_out (fp32)
    gemm_lds<0><<<dim3(C_/128, M_/128), 256, 0, stream>>>(
        attnb, wtout, out, C_, C_, nullptr, nullptr, nullptr);
}